// Round 3
// baseline (381.299 us; speedup 1.0000x reference)
//
#include <hip/hip_runtime.h>
#include <hip/hip_bf16.h>

typedef __attribute__((ext_vector_type(8))) short short8;
typedef __attribute__((ext_vector_type(4))) float f32x4;
typedef __hip_bfloat16 bf16;

#define D_MODEL 1024
#define D_INNER 2048
#define DT_RANK 64
#define D_STATE 16
#define B_SZ 2
#define L_SEQ 1024
#define NSEG 16
#define SL 64   /* L_SEQ / NSEG */

__device__ __forceinline__ float b2f(bf16 x){ return __bfloat162float(x); }
__device__ __forceinline__ bf16  f2b(float x){ return __float2bfloat16(x); }

__device__ __forceinline__ void cvt_store8(bf16* dst, const float* s){
  union { short8 v; bf16 e[8]; } u;
  #pragma unroll
  for (int i = 0; i < 8; i++) u.e[i] = f2b(s[i]);
  *(short8*)dst = u.v;
}

__device__ __forceinline__ short8 ld8_f32(const float* p){
  float b[8];
  *(float4*)&b[0] = *(const float4*)p;
  *(float4*)&b[4] = *(const float4*)(p + 4);
  union { short8 v; bf16 e[8]; } u;
  #pragma unroll
  for (int i = 0; i < 8; i++) u.e[i] = f2b(b[i]);
  return u.v;
}

// ---------------------------------------------------------------------------
// 128x128 MFMA GEMM: C(MxN) = A(MxK) @ B(NxK)^T.  B is always f32 (external
// weight); A is f32 if AF32 else bf16 (internal ws buffer). fp32 accumulate.
// MODE 0: store f32. MODE 1: store softplus(acc + bias[col]) f32. MODE 2: bf16.
// ---------------------------------------------------------------------------
template<int MODE, int AF32>
__global__ __launch_bounds__(256) void gemm128(const void* __restrict__ Av,
                                               const float* __restrict__ B,
                                               void* __restrict__ Cout,
                                               const float* __restrict__ bias,
                                               int M, int N, int K)
{
  __shared__ bf16 As[128][40];   // row stride 80 B -> 16B-aligned short8, 2-way LDS alias (free)
  __shared__ bf16 Bs[128][40];
  const int bm = blockIdx.y * 128, bn = blockIdx.x * 128;
  const int tid  = threadIdx.x;
  const int lane = tid & 63, wave = tid >> 6;
  const int wm = (wave & 1) * 64, wn = (wave >> 1) * 64;
  const int r = lane & 15, q = lane >> 4;
  const int srow = tid >> 1, scol = (tid & 1) * 16;   // staging: 2 threads per row

  const float* gbf = B + (size_t)(bn + srow) * K + scol;
  const float* gaf = (const float*)Av + (size_t)(bm + srow) * K + scol;
  const bf16*  gab = (const bf16*)Av  + (size_t)(bm + srow) * K + scol;

  f32x4 acc[4][4];
  #pragma unroll
  for (int i = 0; i < 4; i++)
    #pragma unroll
    for (int j = 0; j < 4; j++) acc[i][j] = (f32x4){0.f,0.f,0.f,0.f};

  for (int k0 = 0; k0 < K; k0 += 32) {
    if (AF32) {
      float ba[16];
      *(float4*)&ba[0]  = *(const float4*)(gaf + k0);
      *(float4*)&ba[4]  = *(const float4*)(gaf + k0 + 4);
      *(float4*)&ba[8]  = *(const float4*)(gaf + k0 + 8);
      *(float4*)&ba[12] = *(const float4*)(gaf + k0 + 12);
      cvt_store8(&As[srow][scol],     &ba[0]);
      cvt_store8(&As[srow][scol + 8], &ba[8]);
    } else {
      *(uint4*)&As[srow][scol]     = *(const uint4*)(gab + k0);
      *(uint4*)&As[srow][scol + 8] = *(const uint4*)(gab + k0 + 8);
    }
    {
      float bb[16];
      *(float4*)&bb[0]  = *(const float4*)(gbf + k0);
      *(float4*)&bb[4]  = *(const float4*)(gbf + k0 + 4);
      *(float4*)&bb[8]  = *(const float4*)(gbf + k0 + 8);
      *(float4*)&bb[12] = *(const float4*)(gbf + k0 + 12);
      cvt_store8(&Bs[srow][scol],     &bb[0]);
      cvt_store8(&Bs[srow][scol + 8], &bb[8]);
    }
    __syncthreads();
    short8 af[4], bfr[4];
    #pragma unroll
    for (int i = 0; i < 4; i++) af[i]  = *(const short8*)&As[wm + i*16 + r][q*8];
    #pragma unroll
    for (int j = 0; j < 4; j++) bfr[j] = *(const short8*)&Bs[wn + j*16 + r][q*8];
    #pragma unroll
    for (int j = 0; j < 4; j++)
      #pragma unroll
      for (int i = 0; i < 4; i++)
        acc[i][j] = __builtin_amdgcn_mfma_f32_16x16x32_bf16(af[i], bfr[j], acc[i][j], 0, 0, 0);
    __syncthreads();
  }

  #pragma unroll
  for (int i = 0; i < 4; i++)
    #pragma unroll
    for (int j = 0; j < 4; j++)
      #pragma unroll
      for (int t = 0; t < 4; t++) {
        int row = bm + wm + i*16 + q*4 + t;   // C/D: col=lane&15, row=quad*4+reg
        int col = bn + wn + j*16 + r;
        float v = acc[i][j][t];
        if (MODE == 0) {
          ((float*)Cout)[(size_t)row * N + col] = v;
        } else if (MODE == 1) {
          float xv = v + bias[col];
          float sp = (xv > 20.f) ? xv : log1pf(__expf(xv));
          ((float*)Cout)[(size_t)row * N + col] = sp;
        } else {
          ((bf16*)Cout)[(size_t)row * N + col] = f2b(v);
        }
      }
}

// ---------------------------------------------------------------------------
// x_proj GEMM: dbc(2048x96) = xs(2048x2048 bf16) @ x_proj_w(96x2048 f32)^T.
// Also emits bf16 copy of delta_r columns (0..63) for the dt_proj GEMM.
// ---------------------------------------------------------------------------
__global__ __launch_bounds__(256) void gemm_xproj(const bf16* __restrict__ A,
                                                  const float* __restrict__ W,
                                                  float* __restrict__ dbc,
                                                  bf16* __restrict__ dr)
{
  const int K = D_INNER;
  const int lane = threadIdx.x & 63, wave = threadIdx.x >> 6;
  const int mt = blockIdx.y * 4 + wave;   // 0..127
  const int nt = blockIdx.x;              // 0..5
  const int r = lane & 15, q = lane >> 4;
  const bf16*  pa = A + (size_t)(mt*16 + r) * K + q*8;
  const float* pb = W + (size_t)(nt*16 + r) * K + q*8;
  f32x4 a0 = {0.f,0.f,0.f,0.f}, a1 = a0, a2 = a0, a3 = a0;
  for (int k0 = 0; k0 < K; k0 += 128) {
    short8 x0 = *(const short8*)(pa + k0);
    short8 x1 = *(const short8*)(pa + k0 + 32);
    short8 x2 = *(const short8*)(pa + k0 + 64);
    short8 x3 = *(const short8*)(pa + k0 + 96);
    short8 w0 = ld8_f32(pb + k0);
    short8 w1 = ld8_f32(pb + k0 + 32);
    short8 w2 = ld8_f32(pb + k0 + 64);
    short8 w3 = ld8_f32(pb + k0 + 96);
    a0 = __builtin_amdgcn_mfma_f32_16x16x32_bf16(x0, w0, a0, 0, 0, 0);
    a1 = __builtin_amdgcn_mfma_f32_16x16x32_bf16(x1, w1, a1, 0, 0, 0);
    a2 = __builtin_amdgcn_mfma_f32_16x16x32_bf16(x2, w2, a2, 0, 0, 0);
    a3 = __builtin_amdgcn_mfma_f32_16x16x32_bf16(x3, w3, a3, 0, 0, 0);
  }
  f32x4 acc = (a0 + a1) + (a2 + a3);
  #pragma unroll
  for (int t = 0; t < 4; t++) {
    int row = mt*16 + q*4 + t;
    int col = nt*16 + r;
    dbc[(size_t)row * 96 + col] = acc[t];
    if (col < DT_RANK) dr[(size_t)row * DT_RANK + col] = f2b(acc[t]);
  }
}

// ---------------------------------------------------------------------------
// Depthwise causal conv (D_CONV=4) + bias + silu. xz (b*L, 4096) bf16 ws.
// ---------------------------------------------------------------------------
__global__ __launch_bounds__(256) void conv_silu_k(const bf16* __restrict__ xz,
                                                   const float* __restrict__ cw,
                                                   const float* __restrict__ cb,
                                                   bf16* __restrict__ xs_b)
{
  int idx = blockIdx.x * 256 + threadIdx.x;   // over B*L*D_INNER
  int d  = idx & (D_INNER - 1);
  int bl = idx >> 11;
  int l  = bl & (L_SEQ - 1);
  float acc = cb[d];
  #pragma unroll
  for (int j = 0; j < 4; ++j) {
    int lp = l - 3 + j;
    if (lp >= 0) acc += cw[d*4 + j] * b2f(xz[(size_t)(bl - 3 + j) * (2*D_INNER) + d]);
  }
  float s = acc / (1.f + __expf(-acc));
  xs_b[idx] = f2b(s);
}

// ---------------------------------------------------------------------------
// Scan pass 1: per-segment local scan from h=0 -> h_end and segment Sum(delta).
// ---------------------------------------------------------------------------
__global__ __launch_bounds__(256) void scan_pass1(const float* __restrict__ delta,
                                                  const bf16* __restrict__ xs,
                                                  const float* __restrict__ dbc,
                                                  const float* __restrict__ A_log,
                                                  float* __restrict__ hseg,
                                                  float* __restrict__ Stot)
{
  __shared__ float bcs[SL][32];
  const int d   = blockIdx.x * 256 + threadIdx.x;
  const int seg = blockIdx.y, b = blockIdx.z;
  for (int i = threadIdx.x; i < SL*32; i += 256) {
    int l = i >> 5, c = i & 31;
    bcs[l][c] = dbc[((size_t)b*L_SEQ + seg*SL + l)*96 + DT_RANK + c];
  }
  __syncthreads();
  float An[16], h[16];
  #pragma unroll
  for (int n = 0; n < 16; n++) { An[n] = -__expf(A_log[d*16 + n]); h[n] = 0.f; }
  float S = 0.f;
  for (int li = 0; li < SL; ++li) {
    size_t bl = (size_t)b * L_SEQ + seg*SL + li;
    float dv = delta[bl*D_INNER + d];
    float xv = b2f(xs[bl*D_INNER + d]);
    S += dv;
    float dx = dv * xv;
    #pragma unroll
    for (int n = 0; n < 16; n++)
      h[n] = __expf(dv * An[n]) * h[n] + dx * bcs[li][n];
  }
  float* hp = hseg + (((size_t)seg*B_SZ + b)*D_INNER + d) * 16;
  #pragma unroll
  for (int n = 0; n < 16; n++) hp[n] = h[n];
  Stot[((size_t)seg*B_SZ + b)*D_INNER + d] = S;
}

// ---------------------------------------------------------------------------
// Scan pass 2: sequential combine across segments. hseg[s] := true h0 of seg s.
// ---------------------------------------------------------------------------
__global__ __launch_bounds__(256) void scan_combine(const float* __restrict__ Stot,
                                                    float* __restrict__ hseg,
                                                    const float* __restrict__ A_log)
{
  int idx = blockIdx.x * 256 + threadIdx.x;   // B*D_INNER threads
  int d = idx & (D_INNER - 1), b = idx >> 11;
  float An[16], H[16];
  #pragma unroll
  for (int n = 0; n < 16; n++) { An[n] = -__expf(A_log[d*16 + n]); H[n] = 0.f; }
  for (int s = 0; s < NSEG; s++) {
    float* hp = hseg + (((size_t)s*B_SZ + b)*D_INNER + d) * 16;
    float St = Stot[((size_t)s*B_SZ + b)*D_INNER + d];
    #pragma unroll
    for (int n = 0; n < 16; n++) {
      float decay = __expf(An[n] * St);
      float hloc = hp[n];
      float Hn = H[n];
      hp[n] = Hn;                       // true h0 entering segment s
      H[n] = decay*Hn + hloc;           // advance to next segment
    }
  }
}

// ---------------------------------------------------------------------------
// Scan pass 3: re-run local recurrence from true h0 (exact), fuse y + D*xs,
// gate with silu(z), write bf16 outin.
// ---------------------------------------------------------------------------
__global__ __launch_bounds__(256) void scan_pass3(const float* __restrict__ delta,
                                                  const bf16* __restrict__ xs,
                                                  const float* __restrict__ dbc,
                                                  const float* __restrict__ A_log,
                                                  const float* __restrict__ hseg,
                                                  const bf16* __restrict__ xz,
                                                  const float* __restrict__ Dw,
                                                  bf16* __restrict__ outin)
{
  __shared__ float bcs[SL][32];
  const int d   = blockIdx.x * 256 + threadIdx.x;
  const int seg = blockIdx.y, b = blockIdx.z;
  for (int i = threadIdx.x; i < SL*32; i += 256) {
    int l = i >> 5, c = i & 31;
    bcs[l][c] = dbc[((size_t)b*L_SEQ + seg*SL + l)*96 + DT_RANK + c];
  }
  __syncthreads();
  float An[16], h[16];
  const float* hp = hseg + (((size_t)seg*B_SZ + b)*D_INNER + d) * 16;
  #pragma unroll
  for (int n = 0; n < 16; n++) { An[n] = -__expf(A_log[d*16 + n]); h[n] = hp[n]; }
  const float Dv = Dw[d];
  for (int li = 0; li < SL; ++li) {
    size_t bl = (size_t)b * L_SEQ + seg*SL + li;
    float dv = delta[bl*D_INNER + d];
    float xv = b2f(xs[bl*D_INNER + d]);
    float dx = dv * xv;
    float y = 0.f;
    #pragma unroll
    for (int n = 0; n < 16; n++) {
      h[n] = __expf(dv * An[n]) * h[n] + dx * bcs[li][n];
      y   += h[n] * bcs[li][16 + n];
    }
    y += Dv * xv;
    float z = b2f(xz[bl*(size_t)(2*D_INNER) + D_INNER + d]);
    float g = z / (1.f + __expf(-z));
    outin[bl*D_INNER + d] = f2b(y * g);
  }
}

// ---------------------------------------------------------------------------
extern "C" void kernel_launch(void* const* d_in, const int* in_sizes, int n_in,
                              void* d_out, int out_size, void* d_ws, size_t ws_size,
                              hipStream_t stream)
{
  const float* x      = (const float*)d_in[0];
  const float* in_w   = (const float*)d_in[1];
  const float* conv_w = (const float*)d_in[2];
  const float* conv_b = (const float*)d_in[3];
  const float* xp_w   = (const float*)d_in[4];
  const float* dt_w   = (const float*)d_in[5];
  const float* dt_b   = (const float*)d_in[6];
  const float* A_log  = (const float*)d_in[7];
  const float* Dw     = (const float*)d_in[8];
  const float* out_w  = (const float*)d_in[9];
  float* out = (float*)d_out;

  // workspace layout (~53.3 MB total)
  char* p = (char*)d_ws;
  bf16*  xz    = (bf16*)p;  p += (size_t)B_SZ*L_SEQ*2*D_INNER*2;   // 16 MB
  bf16*  xs_b  = (bf16*)p;  p += (size_t)B_SZ*L_SEQ*D_INNER*2;     //  8 MB
  float* dbc   = (float*)p; p += (size_t)B_SZ*L_SEQ*96*4;          // .75MB
  bf16*  dr    = (bf16*)p;  p += (size_t)B_SZ*L_SEQ*DT_RANK*2;     // .25MB
  float* delta = (float*)p; p += (size_t)B_SZ*L_SEQ*D_INNER*4;     // 16 MB
  float* hseg  = (float*)p; p += (size_t)NSEG*B_SZ*D_INNER*16*4;   //  4 MB
  float* Stot  = (float*)p; p += (size_t)NSEG*B_SZ*D_INNER*4;      // .25MB
  bf16*  outin = (bf16*)p;  p += (size_t)B_SZ*L_SEQ*D_INNER*2;     //  8 MB

  const int M = B_SZ * L_SEQ;   // 2048

  // 1) xz = x @ in_proj_w^T        (2048 x 4096, K=1024), A f32 -> bf16 out
  gemm128<2,1><<<dim3(2*D_INNER/128, M/128), 256, 0, stream>>>(x, in_w, xz, nullptr, M, 2*D_INNER, D_MODEL);
  // 2) depthwise causal conv + silu -> xs (bf16)
  conv_silu_k<<<(M*D_INNER)/256, 256, 0, stream>>>(xz, conv_w, conv_b, xs_b);
  // 3) dbc = xs @ x_proj_w^T       (2048 x 96, K=2048)
  gemm_xproj<<<dim3(6, M/64), 256, 0, stream>>>(xs_b, xp_w, dbc, dr);
  // 4) delta = softplus(dr @ dt_proj_w^T + dt_b)  (2048 x 2048, K=64) -> f32
  gemm128<1,0><<<dim3(D_INNER/128, M/128), 256, 0, stream>>>(dr, dt_w, delta, dt_b, M, D_INNER, DT_RANK);
  // 5) chunked selective scan (exact two-sweep decomposition)
  scan_pass1<<<dim3(D_INNER/256, NSEG, B_SZ), 256, 0, stream>>>(delta, xs_b, dbc, A_log, hseg, Stot);
  scan_combine<<<(B_SZ*D_INNER)/256, 256, 0, stream>>>(Stot, hseg, A_log);
  scan_pass3<<<dim3(D_INNER/256, NSEG, B_SZ), 256, 0, stream>>>(delta, xs_b, dbc, A_log, hseg, xz, Dw, outin);
  // 6) out = outin @ out_proj_w^T  (2048 x 1024, K=2048) -> f32 d_out
  gemm128<0,0><<<dim3(D_MODEL/128, M/128), 256, 0, stream>>>(outin, out_w, out, nullptr, M, D_MODEL, D_INNER);
}

// Round 4
// 317.861 us; speedup vs baseline: 1.1996x; 1.1996x over previous
//
#include <hip/hip_runtime.h>
#include <hip/hip_bf16.h>

typedef __attribute__((ext_vector_type(8))) short short8;
typedef __attribute__((ext_vector_type(4))) float f32x4;
typedef __hip_bfloat16 bf16;

#define D_MODEL 1024
#define D_INNER 2048
#define DT_RANK 64
#define D_STATE 16
#define B_SZ 2
#define L_SEQ 1024
#define NSEG 16
#define SL 64   /* L_SEQ / NSEG */

__device__ __forceinline__ float b2f(bf16 x){ return __bfloat162float(x); }
__device__ __forceinline__ bf16  f2b(float x){ return __float2bfloat16(x); }

__device__ __forceinline__ void cvt_store8(bf16* dst, const float* s){
  union { short8 v; bf16 e[8]; } u;
  #pragma unroll
  for (int i = 0; i < 8; i++) u.e[i] = f2b(s[i]);
  *(short8*)dst = u.v;
}

__device__ __forceinline__ void gl_lds16(const bf16* g, bf16* l){
  __builtin_amdgcn_global_load_lds((const __attribute__((address_space(1))) unsigned int*)g,
                                   (__attribute__((address_space(3))) unsigned int*)l, 16, 0, 0);
}

// ---------------------------------------------------------------------------
// f32 -> bf16 bulk convert, 5 segments packed in one launch. Chunk = 8 floats.
// ---------------------------------------------------------------------------
__global__ __launch_bounds__(256) void cvt5_k(const float* s0, bf16* d0, int c0,
                                              const float* s1, bf16* d1, int c1,
                                              const float* s2, bf16* d2, int c2,
                                              const float* s3, bf16* d3, int c3,
                                              const float* s4, bf16* d4, int c4)
{
  int i = blockIdx.x * 256 + threadIdx.x;
  const float* s; bf16* d; int off;
  if      (i < c0) { s = s0; d = d0; off = i; }
  else if (i < c1) { s = s1; d = d1; off = i - c0; }
  else if (i < c2) { s = s2; d = d2; off = i - c1; }
  else if (i < c3) { s = s3; d = d3; off = i - c2; }
  else if (i < c4) { s = s4; d = d4; off = i - c3; }
  else return;
  float b[8];
  *(float4*)&b[0] = *(const float4*)(s + (size_t)off * 8);
  *(float4*)&b[4] = *(const float4*)(s + (size_t)off * 8 + 4);
  cvt_store8(d + (size_t)off * 8, b);
}

// ---------------------------------------------------------------------------
// m97-style MFMA GEMM: C(MxN) = A(MxK) @ B(NxK)^T, bf16 in, fp32 accum.
// BM=128, BN=JT*32 (JT=4 -> 128, JT=2 -> 64). global_load_lds(16B) staging into
// unpadded [rows][32] LDS tiles (wave-uniform base + lane*16 ordering).
// MODE 0: f32 store. MODE 1: softplus(acc+bias[col]) f32. MODE 2: bf16 store.
// ---------------------------------------------------------------------------
template<int MODE, int JT>
__global__ __launch_bounds__(256) void gemm_glds(const bf16* __restrict__ A,
                                                 const bf16* __restrict__ B,
                                                 void* __restrict__ Cout,
                                                 const float* __restrict__ bias,
                                                 int M, int N, int K)
{
  constexpr int BN = JT * 32;
  constexpr int BI = BN / 64;             // B staging instrs per thread (1 or 2)
  __shared__ bf16 As[128 * 32];
  __shared__ bf16 Bs[BN * 32];
  const int bm = blockIdx.y * 128, bn = blockIdx.x * BN;
  const int tid  = threadIdx.x;
  const int lane = tid & 63, wave = tid >> 6;
  const int wm = (wave & 1) * 64, wn = (wave >> 1) * (JT * 16);
  const int r = lane & 15, q = lane >> 4;

  // staging sources: chunk c = i*256 + tid covers row c>>2, cols (c&3)*8..+7
  const bf16* asrc[2];
  #pragma unroll
  for (int i = 0; i < 2; i++) {
    int c = i * 256 + tid;
    asrc[i] = A + (size_t)(bm + (c >> 2)) * K + (c & 3) * 8;
  }
  const bf16* bsrc[BI];
  #pragma unroll
  for (int i = 0; i < BI; i++) {
    int c = i * 256 + tid;
    bsrc[i] = B + (size_t)(bn + (c >> 2)) * K + (c & 3) * 8;
  }

  f32x4 acc[4][JT];
  #pragma unroll
  for (int i = 0; i < 4; i++)
    #pragma unroll
    for (int j = 0; j < JT; j++) acc[i][j] = (f32x4){0.f,0.f,0.f,0.f};

  for (int k0 = 0; k0 < K; k0 += 32) {
    #pragma unroll
    for (int i = 0; i < 2; i++)
      gl_lds16(asrc[i] + k0, &As[(i * 256 + tid) * 8]);
    #pragma unroll
    for (int i = 0; i < BI; i++)
      gl_lds16(bsrc[i] + k0, &Bs[(i * 256 + tid) * 8]);
    __syncthreads();
    short8 af[4], bfr[JT];
    #pragma unroll
    for (int i = 0; i < 4; i++)  af[i]  = *(const short8*)&As[(wm + i*16 + r) * 32 + q*8];
    #pragma unroll
    for (int j = 0; j < JT; j++) bfr[j] = *(const short8*)&Bs[(wn + j*16 + r) * 32 + q*8];
    #pragma unroll
    for (int j = 0; j < JT; j++)
      #pragma unroll
      for (int i = 0; i < 4; i++)
        acc[i][j] = __builtin_amdgcn_mfma_f32_16x16x32_bf16(af[i], bfr[j], acc[i][j], 0, 0, 0);
    __syncthreads();
  }

  #pragma unroll
  for (int i = 0; i < 4; i++)
    #pragma unroll
    for (int j = 0; j < JT; j++)
      #pragma unroll
      for (int t = 0; t < 4; t++) {
        int row = bm + wm + i*16 + q*4 + t;   // C/D: col=lane&15, row=quad*4+reg
        int col = bn + wn + j*16 + r;
        float v = acc[i][j][t];
        if (MODE == 0) {
          ((float*)Cout)[(size_t)row * N + col] = v;
        } else if (MODE == 1) {
          float xv = v + bias[col];
          float sp = (xv > 20.f) ? xv : log1pf(__expf(xv));
          ((float*)Cout)[(size_t)row * N + col] = sp;
        } else {
          ((bf16*)Cout)[(size_t)row * N + col] = f2b(v);
        }
      }
}

// ---------------------------------------------------------------------------
// x_proj GEMM: dbc(2048x96) = xs(2048x2048 bf16) @ x_proj_w(96x2048 bf16)^T.
// Also emits bf16 copy of delta_r columns (0..63) for the dt_proj GEMM.
// ---------------------------------------------------------------------------
__global__ __launch_bounds__(256) void gemm_xproj(const bf16* __restrict__ A,
                                                  const bf16* __restrict__ W,
                                                  float* __restrict__ dbc,
                                                  bf16* __restrict__ dr)
{
  const int K = D_INNER;
  const int lane = threadIdx.x & 63, wave = threadIdx.x >> 6;
  const int mt = blockIdx.y * 4 + wave;   // 0..127
  const int nt = blockIdx.x;              // 0..5
  const int r = lane & 15, q = lane >> 4;
  const bf16* pa = A + (size_t)(mt*16 + r) * K + q*8;
  const bf16* pb = W + (size_t)(nt*16 + r) * K + q*8;
  f32x4 a0 = {0.f,0.f,0.f,0.f}, a1 = a0, a2 = a0, a3 = a0;
  for (int k0 = 0; k0 < K; k0 += 128) {
    short8 x0 = *(const short8*)(pa + k0);
    short8 w0 = *(const short8*)(pb + k0);
    short8 x1 = *(const short8*)(pa + k0 + 32);
    short8 w1 = *(const short8*)(pb + k0 + 32);
    short8 x2 = *(const short8*)(pa + k0 + 64);
    short8 w2 = *(const short8*)(pb + k0 + 64);
    short8 x3 = *(const short8*)(pa + k0 + 96);
    short8 w3 = *(const short8*)(pb + k0 + 96);
    a0 = __builtin_amdgcn_mfma_f32_16x16x32_bf16(x0, w0, a0, 0, 0, 0);
    a1 = __builtin_amdgcn_mfma_f32_16x16x32_bf16(x1, w1, a1, 0, 0, 0);
    a2 = __builtin_amdgcn_mfma_f32_16x16x32_bf16(x2, w2, a2, 0, 0, 0);
    a3 = __builtin_amdgcn_mfma_f32_16x16x32_bf16(x3, w3, a3, 0, 0, 0);
  }
  f32x4 acc = (a0 + a1) + (a2 + a3);
  #pragma unroll
  for (int t = 0; t < 4; t++) {
    int row = mt*16 + q*4 + t;
    int col = nt*16 + r;
    dbc[(size_t)row * 96 + col] = acc[t];
    if (col < DT_RANK) dr[(size_t)row * DT_RANK + col] = f2b(acc[t]);
  }
}

// ---------------------------------------------------------------------------
// Depthwise causal conv (D_CONV=4) + bias + silu. xz (b*L, 4096) bf16 ws.
// ---------------------------------------------------------------------------
__global__ __launch_bounds__(256) void conv_silu_k(const bf16* __restrict__ xz,
                                                   const float* __restrict__ cw,
                                                   const float* __restrict__ cb,
                                                   bf16* __restrict__ xs_b)
{
  int idx = blockIdx.x * 256 + threadIdx.x;   // over B*L*D_INNER
  int d  = idx & (D_INNER - 1);
  int bl = idx >> 11;
  int l  = bl & (L_SEQ - 1);
  float acc = cb[d];
  #pragma unroll
  for (int j = 0; j < 4; ++j) {
    int lp = l - 3 + j;
    if (lp >= 0) acc += cw[d*4 + j] * b2f(xz[(size_t)(bl - 3 + j) * (2*D_INNER) + d]);
  }
  float s = acc / (1.f + __expf(-acc));
  xs_b[idx] = f2b(s);
}

// ---------------------------------------------------------------------------
// Scan pass 1: per-segment local scan from h=0 -> h_end and segment Sum(delta).
// ---------------------------------------------------------------------------
__global__ __launch_bounds__(256) void scan_pass1(const float* __restrict__ delta,
                                                  const bf16* __restrict__ xs,
                                                  const float* __restrict__ dbc,
                                                  const float* __restrict__ A_log,
                                                  float* __restrict__ hseg,
                                                  float* __restrict__ Stot)
{
  __shared__ float bcs[SL][32];
  const int d   = blockIdx.x * 256 + threadIdx.x;
  const int seg = blockIdx.y, b = blockIdx.z;
  for (int i = threadIdx.x; i < SL*32; i += 256) {
    int l = i >> 5, c = i & 31;
    bcs[l][c] = dbc[((size_t)b*L_SEQ + seg*SL + l)*96 + DT_RANK + c];
  }
  __syncthreads();
  float An[16], h[16];
  #pragma unroll
  for (int n = 0; n < 16; n++) { An[n] = -__expf(A_log[d*16 + n]); h[n] = 0.f; }
  float S = 0.f;
  for (int li = 0; li < SL; ++li) {
    size_t bl = (size_t)b * L_SEQ + seg*SL + li;
    float dv = delta[bl*D_INNER + d];
    float xv = b2f(xs[bl*D_INNER + d]);
    S += dv;
    float dx = dv * xv;
    #pragma unroll
    for (int n = 0; n < 16; n++)
      h[n] = __expf(dv * An[n]) * h[n] + dx * bcs[li][n];
  }
  float* hp = hseg + (((size_t)seg*B_SZ + b)*D_INNER + d) * 16;
  #pragma unroll
  for (int n = 0; n < 16; n++) hp[n] = h[n];
  Stot[((size_t)seg*B_SZ + b)*D_INNER + d] = S;
}

// ---------------------------------------------------------------------------
// Scan pass 2: sequential combine across segments. hseg[s] := true h0 of seg s.
// ---------------------------------------------------------------------------
__global__ __launch_bounds__(256) void scan_combine(const float* __restrict__ Stot,
                                                    float* __restrict__ hseg,
                                                    const float* __restrict__ A_log)
{
  int idx = blockIdx.x * 256 + threadIdx.x;   // B*D_INNER threads
  int d = idx & (D_INNER - 1), b = idx >> 11;
  float An[16], H[16];
  #pragma unroll
  for (int n = 0; n < 16; n++) { An[n] = -__expf(A_log[d*16 + n]); H[n] = 0.f; }
  for (int s = 0; s < NSEG; s++) {
    float* hp = hseg + (((size_t)s*B_SZ + b)*D_INNER + d) * 16;
    float St = Stot[((size_t)s*B_SZ + b)*D_INNER + d];
    #pragma unroll
    for (int n = 0; n < 16; n++) {
      float decay = __expf(An[n] * St);
      float hloc = hp[n];
      float Hn = H[n];
      hp[n] = Hn;                       // true h0 entering segment s
      H[n] = decay*Hn + hloc;           // advance to next segment
    }
  }
}

// ---------------------------------------------------------------------------
// Scan pass 3: re-run local recurrence from true h0 (exact), fuse y + D*xs,
// gate with silu(z), write bf16 outin.
// ---------------------------------------------------------------------------
__global__ __launch_bounds__(256) void scan_pass3(const float* __restrict__ delta,
                                                  const bf16* __restrict__ xs,
                                                  const float* __restrict__ dbc,
                                                  const float* __restrict__ A_log,
                                                  const float* __restrict__ hseg,
                                                  const bf16* __restrict__ xz,
                                                  const float* __restrict__ Dw,
                                                  bf16* __restrict__ outin)
{
  __shared__ float bcs[SL][32];
  const int d   = blockIdx.x * 256 + threadIdx.x;
  const int seg = blockIdx.y, b = blockIdx.z;
  for (int i = threadIdx.x; i < SL*32; i += 256) {
    int l = i >> 5, c = i & 31;
    bcs[l][c] = dbc[((size_t)b*L_SEQ + seg*SL + l)*96 + DT_RANK + c];
  }
  __syncthreads();
  float An[16], h[16];
  const float* hp = hseg + (((size_t)seg*B_SZ + b)*D_INNER + d) * 16;
  #pragma unroll
  for (int n = 0; n < 16; n++) { An[n] = -__expf(A_log[d*16 + n]); h[n] = hp[n]; }
  const float Dv = Dw[d];
  for (int li = 0; li < SL; ++li) {
    size_t bl = (size_t)b * L_SEQ + seg*SL + li;
    float dv = delta[bl*D_INNER + d];
    float xv = b2f(xs[bl*D_INNER + d]);
    float dx = dv * xv;
    float y = 0.f;
    #pragma unroll
    for (int n = 0; n < 16; n++) {
      h[n] = __expf(dv * An[n]) * h[n] + dx * bcs[li][n];
      y   += h[n] * bcs[li][16 + n];
    }
    y += Dv * xv;
    float z = b2f(xz[bl*(size_t)(2*D_INNER) + D_INNER + d]);
    float g = z / (1.f + __expf(-z));
    outin[bl*D_INNER + d] = f2b(y * g);
  }
}

// ---------------------------------------------------------------------------
extern "C" void kernel_launch(void* const* d_in, const int* in_sizes, int n_in,
                              void* d_out, int out_size, void* d_ws, size_t ws_size,
                              hipStream_t stream)
{
  const float* x      = (const float*)d_in[0];
  const float* in_w   = (const float*)d_in[1];
  const float* conv_w = (const float*)d_in[2];
  const float* conv_b = (const float*)d_in[3];
  const float* xp_w   = (const float*)d_in[4];
  const float* dt_w   = (const float*)d_in[5];
  const float* dt_b   = (const float*)d_in[6];
  const float* A_log  = (const float*)d_in[7];
  const float* Dw     = (const float*)d_in[8];
  const float* out_w  = (const float*)d_in[9];
  float* out = (float*)d_out;

  // workspace layout (~70 MB total)
  char* p = (char*)d_ws;
  bf16*  xz    = (bf16*)p;  p += (size_t)B_SZ*L_SEQ*2*D_INNER*2;   // 16 MB
  bf16*  xs_b  = (bf16*)p;  p += (size_t)B_SZ*L_SEQ*D_INNER*2;     //  8 MB
  float* dbc   = (float*)p; p += (size_t)B_SZ*L_SEQ*96*4;          // .75MB
  bf16*  dr    = (bf16*)p;  p += (size_t)B_SZ*L_SEQ*DT_RANK*2;     // .25MB
  float* delta = (float*)p; p += (size_t)B_SZ*L_SEQ*D_INNER*4;     // 16 MB
  float* hseg  = (float*)p; p += (size_t)NSEG*B_SZ*D_INNER*16*4;   //  4 MB
  float* Stot  = (float*)p; p += (size_t)NSEG*B_SZ*D_INNER*4;      // .25MB
  bf16*  outin = (bf16*)p;  p += (size_t)B_SZ*L_SEQ*D_INNER*2;     //  8 MB
  bf16*  xb    = (bf16*)p;  p += (size_t)B_SZ*L_SEQ*D_MODEL*2;     //  4 MB
  bf16*  in_wb = (bf16*)p;  p += (size_t)2*D_INNER*D_MODEL*2;      //  8 MB
  bf16*  xp_wb = (bf16*)p;  p += (size_t)(DT_RANK+2*D_STATE)*D_INNER*2; // .375MB
  bf16*  dt_wb = (bf16*)p;  p += (size_t)D_INNER*DT_RANK*2;        // .25MB
  bf16*  ow_b  = (bf16*)p;  p += (size_t)D_MODEL*D_INNER*2;        //  4 MB

  const int M = B_SZ * L_SEQ;   // 2048

  // 0) convert f32 inputs used by GEMMs to bf16 (chunk = 8 floats)
  //    chunks: x 262144, in_w 524288, xp_w 24576, dt_w 16384, out_w 262144
  cvt5_k<<<4256, 256, 0, stream>>>(x, xb, 262144,
                                   in_w, in_wb, 786432,
                                   xp_w, xp_wb, 811008,
                                   dt_w, dt_wb, 827392,
                                   out_w, ow_b, 1089536);
  // 1) xz = x @ in_proj_w^T        (2048 x 4096, K=1024) -> bf16
  gemm_glds<2,4><<<dim3(2*D_INNER/128, M/128), 256, 0, stream>>>(xb, in_wb, xz, nullptr, M, 2*D_INNER, D_MODEL);
  // 2) depthwise causal conv + silu -> xs (bf16)
  conv_silu_k<<<(M*D_INNER)/256, 256, 0, stream>>>(xz, conv_w, conv_b, xs_b);
  // 3) dbc = xs @ x_proj_w^T       (2048 x 96, K=2048)
  gemm_xproj<<<dim3(6, M/64), 256, 0, stream>>>(xs_b, xp_wb, dbc, dr);
  // 4) delta = softplus(dr @ dt_proj_w^T + dt_b)  (2048 x 2048, K=64) -> f32
  gemm_glds<1,4><<<dim3(D_INNER/128, M/128), 256, 0, stream>>>(dr, dt_wb, delta, dt_b, M, D_INNER, DT_RANK);
  // 5) chunked selective scan (exact two-sweep decomposition)
  scan_pass1<<<dim3(D_INNER/256, NSEG, B_SZ), 256, 0, stream>>>(delta, xs_b, dbc, A_log, hseg, Stot);
  scan_combine<<<(B_SZ*D_INNER)/256, 256, 0, stream>>>(Stot, hseg, A_log);
  scan_pass3<<<dim3(D_INNER/256, NSEG, B_SZ), 256, 0, stream>>>(delta, xs_b, dbc, A_log, hseg, xz, Dw, outin);
  // 6) out = outin @ out_proj_w^T  (2048 x 1024, K=2048) -> f32 d_out, BN=64
  gemm_glds<0,2><<<dim3(D_MODEL/64, M/128), 256, 0, stream>>>(outin, ow_b, out, nullptr, M, D_MODEL, D_INNER);
}

// Round 5
// 268.881 us; speedup vs baseline: 1.4181x; 1.1822x over previous
//
#include <hip/hip_runtime.h>
#include <hip/hip_bf16.h>

typedef __attribute__((ext_vector_type(8))) short short8;
typedef __attribute__((ext_vector_type(4))) float f32x4;
typedef __hip_bfloat16 bf16;

#define D_MODEL 1024
#define D_INNER 2048
#define DT_RANK 64
#define D_STATE 16
#define B_SZ 2
#define L_SEQ 1024
#define NSEG 64
#define SL 16   /* L_SEQ / NSEG */

__device__ __forceinline__ float b2f(bf16 x){ return __bfloat162float(x); }
__device__ __forceinline__ bf16  f2b(float x){ return __float2bfloat16(x); }

__device__ __forceinline__ void cvt_store8(bf16* dst, const float* s){
  union { short8 v; bf16 e[8]; } u;
  #pragma unroll
  for (int i = 0; i < 8; i++) u.e[i] = f2b(s[i]);
  *(short8*)dst = u.v;
}

__device__ __forceinline__ void gl_lds16(const bf16* g, bf16* l){
  __builtin_amdgcn_global_load_lds((const __attribute__((address_space(1))) unsigned int*)g,
                                   (__attribute__((address_space(3))) unsigned int*)l, 16, 0, 0);
}

// ---------------------------------------------------------------------------
// f32 -> bf16 bulk convert, 5 segments packed in one launch. Chunk = 8 floats.
// ---------------------------------------------------------------------------
__global__ __launch_bounds__(256) void cvt5_k(const float* s0, bf16* d0, int c0,
                                              const float* s1, bf16* d1, int c1,
                                              const float* s2, bf16* d2, int c2,
                                              const float* s3, bf16* d3, int c3,
                                              const float* s4, bf16* d4, int c4)
{
  int i = blockIdx.x * 256 + threadIdx.x;
  const float* s; bf16* d; int off;
  if      (i < c0) { s = s0; d = d0; off = i; }
  else if (i < c1) { s = s1; d = d1; off = i - c0; }
  else if (i < c2) { s = s2; d = d2; off = i - c1; }
  else if (i < c3) { s = s3; d = d3; off = i - c2; }
  else if (i < c4) { s = s4; d = d4; off = i - c3; }
  else return;
  float b[8];
  *(float4*)&b[0] = *(const float4*)(s + (size_t)off * 8);
  *(float4*)&b[4] = *(const float4*)(s + (size_t)off * 8 + 4);
  cvt_store8(d + (size_t)off * 8, b);
}

// ---------------------------------------------------------------------------
// m97-style MFMA GEMM: C(MxN) = A(MxK) @ B(NxK)^T, bf16 in, fp32 accum.
// BM=128, BN=JT*32 (JT=4 -> 128, JT=2 -> 64). global_load_lds(16B) staging into
// unpadded [rows][32] LDS tiles (wave-uniform base + lane*16 ordering).
// MODE 0: f32 store. MODE 1: softplus(acc+bias[col]) f32. MODE 2: bf16 store.
// ---------------------------------------------------------------------------
template<int MODE, int JT>
__global__ __launch_bounds__(256) void gemm_glds(const bf16* __restrict__ A,
                                                 const bf16* __restrict__ B,
                                                 void* __restrict__ Cout,
                                                 const float* __restrict__ bias,
                                                 int M, int N, int K)
{
  constexpr int BN = JT * 32;
  constexpr int BI = BN / 64;             // B staging instrs per thread (1 or 2)
  __shared__ bf16 As[128 * 32];
  __shared__ bf16 Bs[BN * 32];
  const int bm = blockIdx.y * 128, bn = blockIdx.x * BN;
  const int tid  = threadIdx.x;
  const int lane = tid & 63, wave = tid >> 6;
  const int wm = (wave & 1) * 64, wn = (wave >> 1) * (JT * 16);
  const int r = lane & 15, q = lane >> 4;

  // staging sources: chunk c = i*256 + tid covers row c>>2, cols (c&3)*8..+7
  const bf16* asrc[2];
  #pragma unroll
  for (int i = 0; i < 2; i++) {
    int c = i * 256 + tid;
    asrc[i] = A + (size_t)(bm + (c >> 2)) * K + (c & 3) * 8;
  }
  const bf16* bsrc[BI];
  #pragma unroll
  for (int i = 0; i < BI; i++) {
    int c = i * 256 + tid;
    bsrc[i] = B + (size_t)(bn + (c >> 2)) * K + (c & 3) * 8;
  }

  f32x4 acc[4][JT];
  #pragma unroll
  for (int i = 0; i < 4; i++)
    #pragma unroll
    for (int j = 0; j < JT; j++) acc[i][j] = (f32x4){0.f,0.f,0.f,0.f};

  for (int k0 = 0; k0 < K; k0 += 32) {
    #pragma unroll
    for (int i = 0; i < 2; i++)
      gl_lds16(asrc[i] + k0, &As[(i * 256 + tid) * 8]);
    #pragma unroll
    for (int i = 0; i < BI; i++)
      gl_lds16(bsrc[i] + k0, &Bs[(i * 256 + tid) * 8]);
    __syncthreads();
    short8 af[4], bfr[JT];
    #pragma unroll
    for (int i = 0; i < 4; i++)  af[i]  = *(const short8*)&As[(wm + i*16 + r) * 32 + q*8];
    #pragma unroll
    for (int j = 0; j < JT; j++) bfr[j] = *(const short8*)&Bs[(wn + j*16 + r) * 32 + q*8];
    #pragma unroll
    for (int j = 0; j < JT; j++)
      #pragma unroll
      for (int i = 0; i < 4; i++)
        acc[i][j] = __builtin_amdgcn_mfma_f32_16x16x32_bf16(af[i], bfr[j], acc[i][j], 0, 0, 0);
    __syncthreads();
  }

  #pragma unroll
  for (int i = 0; i < 4; i++)
    #pragma unroll
    for (int j = 0; j < JT; j++)
      #pragma unroll
      for (int t = 0; t < 4; t++) {
        int row = bm + wm + i*16 + q*4 + t;   // C/D: col=lane&15, row=quad*4+reg
        int col = bn + wn + j*16 + r;
        float v = acc[i][j][t];
        if (MODE == 0) {
          ((float*)Cout)[(size_t)row * N + col] = v;
        } else if (MODE == 1) {
          float xv = v + bias[col];
          float sp = (xv > 20.f) ? xv : log1pf(__expf(xv));
          ((float*)Cout)[(size_t)row * N + col] = sp;
        } else {
          ((bf16*)Cout)[(size_t)row * N + col] = f2b(v);
        }
      }
}

// ---------------------------------------------------------------------------
// x_proj GEMM: dbc(2048x96) = xs(2048x2048 bf16) @ x_proj_w(96x2048 bf16)^T.
// Also emits bf16 copy of delta_r columns (0..63) for the dt_proj GEMM.
// ---------------------------------------------------------------------------
__global__ __launch_bounds__(256) void gemm_xproj(const bf16* __restrict__ A,
                                                  const bf16* __restrict__ W,
                                                  float* __restrict__ dbc,
                                                  bf16* __restrict__ dr)
{
  const int K = D_INNER;
  const int lane = threadIdx.x & 63, wave = threadIdx.x >> 6;
  const int mt = blockIdx.y * 4 + wave;   // 0..127
  const int nt = blockIdx.x;              // 0..5
  const int r = lane & 15, q = lane >> 4;
  const bf16* pa = A + (size_t)(mt*16 + r) * K + q*8;
  const bf16* pb = W + (size_t)(nt*16 + r) * K + q*8;
  f32x4 a0 = {0.f,0.f,0.f,0.f}, a1 = a0, a2 = a0, a3 = a0;
  for (int k0 = 0; k0 < K; k0 += 128) {
    short8 x0 = *(const short8*)(pa + k0);
    short8 w0 = *(const short8*)(pb + k0);
    short8 x1 = *(const short8*)(pa + k0 + 32);
    short8 w1 = *(const short8*)(pb + k0 + 32);
    short8 x2 = *(const short8*)(pa + k0 + 64);
    short8 w2 = *(const short8*)(pb + k0 + 64);
    short8 x3 = *(const short8*)(pa + k0 + 96);
    short8 w3 = *(const short8*)(pb + k0 + 96);
    a0 = __builtin_amdgcn_mfma_f32_16x16x32_bf16(x0, w0, a0, 0, 0, 0);
    a1 = __builtin_amdgcn_mfma_f32_16x16x32_bf16(x1, w1, a1, 0, 0, 0);
    a2 = __builtin_amdgcn_mfma_f32_16x16x32_bf16(x2, w2, a2, 0, 0, 0);
    a3 = __builtin_amdgcn_mfma_f32_16x16x32_bf16(x3, w3, a3, 0, 0, 0);
  }
  f32x4 acc = (a0 + a1) + (a2 + a3);
  #pragma unroll
  for (int t = 0; t < 4; t++) {
    int row = mt*16 + q*4 + t;
    int col = nt*16 + r;
    dbc[(size_t)row * 96 + col] = acc[t];
    if (col < DT_RANK) dr[(size_t)row * DT_RANK + col] = f2b(acc[t]);
  }
}

// ---------------------------------------------------------------------------
// Depthwise causal conv (D_CONV=4) + bias + silu. xz (b*L, 4096) bf16 ws.
// ---------------------------------------------------------------------------
__global__ __launch_bounds__(256) void conv_silu_k(const bf16* __restrict__ xz,
                                                   const float* __restrict__ cw,
                                                   const float* __restrict__ cb,
                                                   bf16* __restrict__ xs_b)
{
  int idx = blockIdx.x * 256 + threadIdx.x;   // over B*L*D_INNER
  int d  = idx & (D_INNER - 1);
  int bl = idx >> 11;
  int l  = bl & (L_SEQ - 1);
  float acc = cb[d];
  #pragma unroll
  for (int j = 0; j < 4; ++j) {
    int lp = l - 3 + j;
    if (lp >= 0) acc += cw[d*4 + j] * b2f(xz[(size_t)(bl - 3 + j) * (2*D_INNER) + d]);
  }
  float s = acc / (1.f + __expf(-acc));
  xs_b[idx] = f2b(s);
}

// ---------------------------------------------------------------------------
// Scan pass 1: per-segment local scan from h=0 -> h_end and segment Sum(delta).
// ---------------------------------------------------------------------------
__global__ __launch_bounds__(256) void scan_pass1(const float* __restrict__ delta,
                                                  const bf16* __restrict__ xs,
                                                  const float* __restrict__ dbc,
                                                  const float* __restrict__ A_log,
                                                  float* __restrict__ hseg,
                                                  float* __restrict__ Stot)
{
  __shared__ float bcs[SL][32];
  const int d   = blockIdx.x * 256 + threadIdx.x;
  const int seg = blockIdx.y, b = blockIdx.z;
  for (int i = threadIdx.x; i < SL*32; i += 256) {
    int l = i >> 5, c = i & 31;
    bcs[l][c] = dbc[((size_t)b*L_SEQ + seg*SL + l)*96 + DT_RANK + c];
  }
  __syncthreads();
  float An[16], h[16];
  #pragma unroll
  for (int n = 0; n < 16; n++) { An[n] = -__expf(A_log[d*16 + n]); h[n] = 0.f; }
  float S = 0.f;
  for (int li = 0; li < SL; ++li) {
    size_t bl = (size_t)b * L_SEQ + seg*SL + li;
    float dv = delta[bl*D_INNER + d];
    float xv = b2f(xs[bl*D_INNER + d]);
    S += dv;
    float dx = dv * xv;
    #pragma unroll
    for (int n = 0; n < 16; n++)
      h[n] = __expf(dv * An[n]) * h[n] + dx * bcs[li][n];
  }
  float* hp = hseg + (((size_t)seg*B_SZ + b)*D_INNER + d) * 16;
  #pragma unroll
  for (int n = 0; n < 16; n++) hp[n] = h[n];
  Stot[((size_t)seg*B_SZ + b)*D_INNER + d] = S;
}

// ---------------------------------------------------------------------------
// Scan pass 2: sequential combine across segments, one thread per (b,d,n).
// hseg[s] := true h0 entering segment s. Loads across s are independent
// (prefetchable); only the fma chain is serial.
// ---------------------------------------------------------------------------
__global__ __launch_bounds__(256) void scan_combine(const float* __restrict__ Stot,
                                                    float* __restrict__ hseg,
                                                    const float* __restrict__ A_log)
{
  int idx = blockIdx.x * 256 + threadIdx.x;   // B*D_INNER*16 threads
  int n = idx & 15;
  int d = (idx >> 4) & (D_INNER - 1);
  int b = idx >> 15;
  float An = -__expf(A_log[d*16 + n]);
  float H = 0.f;
  for (int s = 0; s < NSEG; s++) {
    size_t base = ((size_t)s*B_SZ + b)*D_INNER + d;
    float St   = Stot[base];
    float hloc = hseg[base*16 + n];
    hseg[base*16 + n] = H;                 // true h0 entering segment s
    H = __expf(An*St)*H + hloc;            // advance to next segment
  }
}

// ---------------------------------------------------------------------------
// Scan pass 3: re-run local recurrence from true h0 (exact), fuse y + D*xs,
// gate with silu(z), write bf16 outin.
// ---------------------------------------------------------------------------
__global__ __launch_bounds__(256) void scan_pass3(const float* __restrict__ delta,
                                                  const bf16* __restrict__ xs,
                                                  const float* __restrict__ dbc,
                                                  const float* __restrict__ A_log,
                                                  const float* __restrict__ hseg,
                                                  const bf16* __restrict__ xz,
                                                  const float* __restrict__ Dw,
                                                  bf16* __restrict__ outin)
{
  __shared__ float bcs[SL][32];
  const int d   = blockIdx.x * 256 + threadIdx.x;
  const int seg = blockIdx.y, b = blockIdx.z;
  for (int i = threadIdx.x; i < SL*32; i += 256) {
    int l = i >> 5, c = i & 31;
    bcs[l][c] = dbc[((size_t)b*L_SEQ + seg*SL + l)*96 + DT_RANK + c];
  }
  __syncthreads();
  float An[16], h[16];
  const float* hp = hseg + (((size_t)seg*B_SZ + b)*D_INNER + d) * 16;
  #pragma unroll
  for (int n = 0; n < 16; n++) { An[n] = -__expf(A_log[d*16 + n]); h[n] = hp[n]; }
  const float Dv = Dw[d];
  for (int li = 0; li < SL; ++li) {
    size_t bl = (size_t)b * L_SEQ + seg*SL + li;
    float dv = delta[bl*D_INNER + d];
    float xv = b2f(xs[bl*D_INNER + d]);
    float dx = dv * xv;
    float y = 0.f;
    #pragma unroll
    for (int n = 0; n < 16; n++) {
      h[n] = __expf(dv * An[n]) * h[n] + dx * bcs[li][n];
      y   += h[n] * bcs[li][16 + n];
    }
    y += Dv * xv;
    float z = b2f(xz[bl*(size_t)(2*D_INNER) + D_INNER + d]);
    float g = z / (1.f + __expf(-z));
    outin[bl*D_INNER + d] = f2b(y * g);
  }
}

// ---------------------------------------------------------------------------
extern "C" void kernel_launch(void* const* d_in, const int* in_sizes, int n_in,
                              void* d_out, int out_size, void* d_ws, size_t ws_size,
                              hipStream_t stream)
{
  const float* x      = (const float*)d_in[0];
  const float* in_w   = (const float*)d_in[1];
  const float* conv_w = (const float*)d_in[2];
  const float* conv_b = (const float*)d_in[3];
  const float* xp_w   = (const float*)d_in[4];
  const float* dt_w   = (const float*)d_in[5];
  const float* dt_b   = (const float*)d_in[6];
  const float* A_log  = (const float*)d_in[7];
  const float* Dw     = (const float*)d_in[8];
  const float* out_w  = (const float*)d_in[9];
  float* out = (float*)d_out;

  // workspace layout (~70.6 MB). hseg (16 MB) overlays xb+in_wb (12 MB + pad):
  // xb/in_wb are dead after the in_proj GEMM, hseg is written after it.
  char* p = (char*)d_ws;
  bf16*  xz    = (bf16*)p;  p += (size_t)B_SZ*L_SEQ*2*D_INNER*2;   // 16 MB
  bf16*  xs_b  = (bf16*)p;  p += (size_t)B_SZ*L_SEQ*D_INNER*2;     //  8 MB
  float* dbc   = (float*)p; p += (size_t)B_SZ*L_SEQ*96*4;          // .75MB
  bf16*  dr    = (bf16*)p;  p += (size_t)B_SZ*L_SEQ*DT_RANK*2;     // .25MB
  float* delta = (float*)p; p += (size_t)B_SZ*L_SEQ*D_INNER*4;     // 16 MB
  float* Stot  = (float*)p; p += (size_t)NSEG*B_SZ*D_INNER*4;      //  1 MB
  bf16*  outin = (bf16*)p;  p += (size_t)B_SZ*L_SEQ*D_INNER*2;     //  8 MB
  bf16*  xp_wb = (bf16*)p;  p += (size_t)(DT_RANK+2*D_STATE)*D_INNER*2; // .375MB
  bf16*  dt_wb = (bf16*)p;  p += (size_t)D_INNER*DT_RANK*2;        // .25MB
  bf16*  ow_b  = (bf16*)p;  p += (size_t)D_MODEL*D_INNER*2;        //  4 MB
  char* u = p;                                                     // union region, 16 MB
  bf16*  xb    = (bf16*)u;                      // 4 MB  (gemm1 only)
  bf16*  in_wb = (bf16*)(u + (size_t)B_SZ*L_SEQ*D_MODEL*2); // 8 MB (gemm1 only)
  float* hseg  = (float*)u;                     // 16 MB (scan, after gemm1)
  p += (size_t)NSEG*B_SZ*D_INNER*16*4;

  const int M = B_SZ * L_SEQ;   // 2048

  // 0) convert f32 inputs used by GEMMs to bf16 (chunk = 8 floats)
  cvt5_k<<<4256, 256, 0, stream>>>(x, xb, 262144,
                                   in_w, in_wb, 786432,
                                   xp_w, xp_wb, 811008,
                                   dt_w, dt_wb, 827392,
                                   out_w, ow_b, 1089536);
  // 1) xz = x @ in_proj_w^T        (2048 x 4096, K=1024) -> bf16
  gemm_glds<2,4><<<dim3(2*D_INNER/128, M/128), 256, 0, stream>>>(xb, in_wb, xz, nullptr, M, 2*D_INNER, D_MODEL);
  // 2) depthwise causal conv + silu -> xs (bf16)
  conv_silu_k<<<(M*D_INNER)/256, 256, 0, stream>>>(xz, conv_w, conv_b, xs_b);
  // 3) dbc = xs @ x_proj_w^T       (2048 x 96, K=2048)
  gemm_xproj<<<dim3(6, M/64), 256, 0, stream>>>(xs_b, xp_wb, dbc, dr);
  // 4) delta = softplus(dr @ dt_proj_w^T + dt_b)  (2048 x 2048, K=64) -> f32
  gemm_glds<1,4><<<dim3(D_INNER/128, M/128), 256, 0, stream>>>(dr, dt_wb, delta, dt_b, M, D_INNER, DT_RANK);
  // 5) chunked selective scan (exact two-sweep decomposition), 64 segments
  scan_pass1<<<dim3(D_INNER/256, NSEG, B_SZ), 256, 0, stream>>>(delta, xs_b, dbc, A_log, hseg, Stot);
  scan_combine<<<(B_SZ*D_INNER*16)/256, 256, 0, stream>>>(Stot, hseg, A_log);
  scan_pass3<<<dim3(D_INNER/256, NSEG, B_SZ), 256, 0, stream>>>(delta, xs_b, dbc, A_log, hseg, xz, Dw, outin);
  // 6) out = outin @ out_proj_w^T  (2048 x 1024, K=2048) -> f32 d_out, BN=64
  gemm_glds<0,2><<<dim3(D_MODEL/64, M/128), 256, 0, stream>>>(outin, ow_b, out, nullptr, M, D_MODEL, D_INNER);
}